// Round 3
// baseline (187.662 us; speedup 1.0000x reference)
//
#include <hip/hip_runtime.h>
#include <math.h>

#define DD 160
#define HH 160
#define WW 160
#define NB 2
#define NEL (NB*DD*HH*WW)   // 8,192,000 voxels

#define XT 32               // x outputs per block
#define YT 16               // y outputs per block
#define ZC 16               // z outputs per block
#define TXP 16              // lanes in x (each owns 2 x)
#define TYO 8               // threads in y (each owns 2 y)
#define NTHR 128
#define NZCH (DD/ZC)        // 10
#define GX (WW/XT)          // 5
#define GY (HH/YT)          // 10
#define NPART (GX*GY*NB*NZCH)  // 1000

#define HW 38               // halo width (floats)
#define HR 22               // halo rows
#define SPITCH 21           // raw-tile row pitch (float2), padded
#define CPITCH 17           // c5 row pitch (float2), padded

struct G7 { float g[7]; };

// Fully fused separable 3D SSIM, LDS-instruction-optimized:
//  * 4 channels: p, t, (p+t)^2, (p-t)^2  (linear conv recovers E[p^2]+E[t^2]
//    and E[pt]) -- 20% less work everywhere than the naive 5 channels.
//  * float2 x-pairs: all LDS ops are b64, halving LDS instruction count.
//  * y-pairs with streamed dual accumulation: 8 shared c5 rows read once.
//  * z-conv via register ring (6 live slots x 4 ch x 4 columns = 96 VGPRs).
__global__ __launch_bounds__(NTHR) void ssim_fused(
        const float* __restrict__ p, const float* __restrict__ t,
        float* __restrict__ partial, G7 gw) {
    const int tid = threadIdx.x;
    const int txp = tid & (TXP - 1);
    const int tyo = tid >> 4;
    const int x0 = blockIdx.x * XT;
    const int y0 = blockIdx.y * YT;
    const int n  = blockIdx.z / NZCH;
    const int zs = (blockIdx.z % NZCH) * ZC;

    __shared__ float2 sp2[HR][SPITCH];
    __shared__ float2 st2[HR][SPITCH];
    __shared__ float2 c5[4][HR][CPITCH];

    float acc[2][4][6][2];   // [y-out][ch][ring slot][x-out]
#pragma unroll
    for (int yo = 0; yo < 2; ++yo)
#pragma unroll
        for (int ch = 0; ch < 4; ++ch)
#pragma unroll
            for (int j = 0; j < 6; ++j) {
                acc[yo][ch][j][0] = 0.f; acc[yo][ch][j][1] = 0.f;
            }

    const float C1v = 1e-4f, C2v = 9e-4f;
    float ssum = 0.f;
    const int hw = HH * WW;
    const float* pv = p + (size_t)n * DD * hw;
    const float* tv = t + (size_t)n * DD * hw;

    for (int s = zs - 3; s < zs + ZC + 3; ++s) {
        float2 m[2][4];
#pragma unroll
        for (int yo = 0; yo < 2; ++yo)
#pragma unroll
            for (int ch = 0; ch < 4; ++ch) { m[yo][ch].x = 0.f; m[yo][ch].y = 0.f; }

        const bool valid = (s >= 0) && (s < DD);   // block-uniform
        if (valid) {
            const float* pb = pv + (size_t)s * hw;
            const float* tb = tv + (size_t)s * hw;

            // ---- A: stage raw halo tile (38x22), zero pad at edges ----
            float* spf = (float*)&sp2[0][0];
            float* stf = (float*)&st2[0][0];
            for (int i = tid; i < HW * HR; i += NTHR) {
                int r = i / HW, c = i - r * HW;
                int gy = y0 + r - 3, gx = x0 + c - 3;
                float a = 0.f, b = 0.f;
                if ((unsigned)gy < (unsigned)HH && (unsigned)gx < (unsigned)WW) {
                    a = pb[gy * WW + gx];
                    b = tb[gy * WW + gx];
                }
                spf[r * (2 * SPITCH) + c] = a;
                stf[r * (2 * SPITCH) + c] = b;
            }
            __syncthreads();

            // ---- B: x-conv, 2 outputs x 4 channels per row-job ----
            for (int r = tyo; r < HR; r += TYO) {
                const float2* rowp = &sp2[r][0];
                const float2* rowt = &st2[r][0];
                float fa[10], fb[10];
#pragma unroll
                for (int j = 0; j < 5; ++j) {
                    float2 ua = rowp[txp + j]; fa[2*j] = ua.x; fa[2*j+1] = ua.y;
                    float2 ub = rowt[txp + j]; fb[2*j] = ub.x; fb[2*j+1] = ub.y;
                }
                float s0x=0.f,s0y=0.f,s1x=0.f,s1y=0.f,s2x=0.f,s2y=0.f,s3x=0.f,s3y=0.f;
#pragma unroll
                for (int k = 0; k < 7; ++k) {
                    float w = gw.g[k];
                    float a0 = fa[k], a1 = fa[k+1], b0 = fb[k], b1 = fb[k+1];
                    s0x += w * a0; s0y += w * a1;
                    s1x += w * b0; s1y += w * b1;
                    float u0 = a0 + b0, u1 = a1 + b1;
                    float d0 = a0 - b0, d1 = a1 - b1;
                    s2x += w * u0 * u0; s2y += w * u1 * u1;
                    s3x += w * d0 * d0; s3y += w * d1 * d1;
                }
                c5[0][r][txp] = make_float2(s0x, s0y);
                c5[1][r][txp] = make_float2(s1x, s1y);
                c5[2][r][txp] = make_float2(s2x, s2y);
                c5[3][r][txp] = make_float2(s3x, s3y);
            }
            __syncthreads();

            // ---- C: y-conv, stream 8 rows, accumulate both y-outputs ----
#pragma unroll
            for (int r8 = 0; r8 < 8; ++r8) {
                int rr = 2 * tyo + r8;
                float2 r0 = c5[0][rr][txp];
                float2 r1 = c5[1][rr][txp];
                float2 r2 = c5[2][rr][txp];
                float2 r3 = c5[3][rr][txp];
                if (r8 < 7) {
                    float w = gw.g[r8];
                    m[0][0].x += w*r0.x; m[0][0].y += w*r0.y;
                    m[0][1].x += w*r1.x; m[0][1].y += w*r1.y;
                    m[0][2].x += w*r2.x; m[0][2].y += w*r2.y;
                    m[0][3].x += w*r3.x; m[0][3].y += w*r3.y;
                }
                if (r8 > 0) {
                    float w = gw.g[r8 - 1];
                    m[1][0].x += w*r0.x; m[1][0].y += w*r0.y;
                    m[1][1].x += w*r1.x; m[1][1].y += w*r1.y;
                    m[1][2].x += w*r2.x; m[1][2].y += w*r2.y;
                    m[1][3].x += w*r3.x; m[1][3].y += w*r3.y;
                }
            }
            // no barrier here: next iteration's A writes sp2/st2 (disjoint
            // from c5); next B's c5 writes are fenced by next A's barrier.
        }

        // ---- z ring: consume slot0, shift+FMA, refill slot5 ----
        float cons[2][4][2];
#pragma unroll
        for (int yo = 0; yo < 2; ++yo)
#pragma unroll
            for (int ch = 0; ch < 4; ++ch)
#pragma unroll
                for (int xx = 0; xx < 2; ++xx) {
                    float vv = xx ? m[yo][ch].y : m[yo][ch].x;
                    cons[yo][ch][xx]   = acc[yo][ch][0][xx] + gw.g[6] * vv;
                    acc[yo][ch][0][xx] = acc[yo][ch][1][xx] + gw.g[5] * vv;
                    acc[yo][ch][1][xx] = acc[yo][ch][2][xx] + gw.g[4] * vv;
                    acc[yo][ch][2][xx] = acc[yo][ch][3][xx] + gw.g[3] * vv;
                    acc[yo][ch][3][xx] = acc[yo][ch][4][xx] + gw.g[2] * vv;
                    acc[yo][ch][4][xx] = acc[yo][ch][5][xx] + gw.g[1] * vv;
                    acc[yo][ch][5][xx] = gw.g[0] * vv;
                }

        if (s >= zs + 3) {   // output z = s-3
#pragma unroll
            for (int yo = 0; yo < 2; ++yo)
#pragma unroll
                for (int xx = 0; xx < 2; ++xx) {
                    float mu1 = cons[yo][0][xx], mu2 = cons[yo][1][xx];
                    float Eu  = cons[yo][2][xx], Ew  = cons[yo][3][xx];
                    float mu12 = mu1 * mu2, mu1sq = mu1 * mu1, mu2sq = mu2 * mu2;
                    float sumsq = 0.5f  * (Eu + Ew) - mu1sq - mu2sq; // s1+s2
                    float s12   = 0.25f * (Eu - Ew) - mu12;          // sigma12
                    float num = (2.f * mu12 + C1v) * (2.f * s12 + C2v);
                    float den = (mu1sq + mu2sq + C1v) * (sumsq + C2v);
                    ssum += num * __builtin_amdgcn_rcpf(den);
                }
        }
    }

    // ---- block reduction (2 waves) ----
#pragma unroll
    for (int off = 32; off > 0; off >>= 1)
        ssum += __shfl_down(ssum, off, 64);
    __shared__ float wsum[2];
    if ((tid & 63) == 0) wsum[tid >> 6] = ssum;
    __syncthreads();
    if (tid == 0) {
        int bid = (blockIdx.z * GY + blockIdx.y) * GX + blockIdx.x;
        partial[bid] = wsum[0] + wsum[1];
    }
}

__global__ __launch_bounds__(256) void ssim_final(
        const float* __restrict__ partial, float* __restrict__ out) {
    float s = 0.f;
    for (int i = threadIdx.x; i < NPART; i += 256) s += partial[i];
#pragma unroll
    for (int off = 32; off > 0; off >>= 1)
        s += __shfl_down(s, off, 64);
    __shared__ float wsum[4];
    int lane = threadIdx.x & 63, wid = threadIdx.x >> 6;
    if (lane == 0) wsum[wid] = s;
    __syncthreads();
    if (threadIdx.x == 0) {
        float tot = wsum[0] + wsum[1] + wsum[2] + wsum[3];
        out[0] = 1.0f - tot / (float)NEL;
    }
}

extern "C" void kernel_launch(void* const* d_in, const int* in_sizes, int n_in,
                              void* d_out, int out_size, void* d_ws, size_t ws_size,
                              hipStream_t stream) {
    const float* p = (const float*)d_in[0];
    const float* t = (const float*)d_in[1];
    float* out = (float*)d_out;
    float* partial = (float*)d_ws;   // NPART floats

    G7 gw;
    {
        double s = 0.0, sig = 7.0 / 6.0;
        double g[7];
        for (int i = 0; i < 7; ++i) {
            double d = (double)i - 3.0;
            g[i] = exp(-d * d / (2.0 * sig * sig));
            s += g[i];
        }
        for (int i = 0; i < 7; ++i) gw.g[i] = (float)(g[i] / s);
    }

    dim3 grid(GX, GY, NB * NZCH);   // (5, 10, 20) = 1000 blocks
    ssim_fused<<<grid, NTHR, 0, stream>>>(p, t, partial, gw);
    ssim_final<<<1, 256, 0, stream>>>(partial, out);
}

// Round 4
// 153.173 us; speedup vs baseline: 1.2252x; 1.2252x over previous
//
#include <hip/hip_runtime.h>
#include <math.h>

#define DD 160
#define HH 160
#define WW 160
#define NB 2
#define NEL (NB*DD*HH*WW)   // 8,192,000 voxels

#define XT 32               // x outputs per block
#define YT 16               // y outputs per block
#define ZC 16               // z outputs per block
#define NTHR 256
#define NZCH (DD/ZC)        // 10
#define GX (WW/XT)          // 5
#define GY (HH/YT)          // 10
#define NPART (GX*GY*NB*NZCH)  // 1000 blocks -> 4000 waves (~15.6/CU)

#define PCOLS 38            // halo x-positions (32 + 6)
#define HR 22               // halo rows (16 + 6)
#define PPITCH 42           // float2 pitch of staged rows (16B-aligned + pad)
#define CPITCH 33           // float4 pitch of c4 rows (+1 pad)

struct G7 { float g[7]; };

__device__ __forceinline__ float2 f2fma(float s, float2 a, float2 b) {
    return make_float2(fmaf(s, a.x, b.x), fmaf(s, a.y, b.y));
}

// Fully fused separable 3D SSIM, LDS-vectorized:
//  * 4 channels: (p, t) and ((p+t)^2, (p-t)^2), squares formed ONCE at staging.
//  * x-conv: 4 outputs/job from a 10-position window = 5 aligned b128 reads
//    per array; result written as one float4 (all 4 ch) per x -> b128.
//  * y-conv: 2 y-outputs/thread streaming 8 rows = 8 b128 reads / 2 voxels.
//  * z-conv: two float2 register rings per y-output (48 regs total).
__global__ __launch_bounds__(NTHR, 4) void ssim_fused(
        const float* __restrict__ p, const float* __restrict__ t,
        float* __restrict__ partial, G7 gw) {
    const int tid = threadIdx.x;
    const int tx  = tid & 31;            // x output column
    const int tyo = tid >> 5;            // 0..7, owns y = 2tyo, 2tyo+1
    const int x0 = blockIdx.x * XT;
    const int y0 = blockIdx.y * YT;
    const int n  = blockIdx.z / NZCH;
    const int zs = (blockIdx.z % NZCH) * ZC;

    __shared__ float2 spt[HR][PPITCH];   // (p, t)
    __shared__ float2 squ[HR][PPITCH];   // ((p+t)^2, (p-t)^2)
    __shared__ float4 c4[HR][CPITCH];    // x-conv result, 4 ch packed

    // z rings: [y-out][slot], slot5 freshest
    float2 r01[2][6], r23[2][6];
#pragma unroll
    for (int yo = 0; yo < 2; ++yo)
#pragma unroll
        for (int j = 0; j < 6; ++j) {
            r01[yo][j] = make_float2(0.f, 0.f);
            r23[yo][j] = make_float2(0.f, 0.f);
        }

    const float C1v = 1e-4f, C2v = 9e-4f;
    float ssum = 0.f;
    const int hw = HH * WW;
    const float* pv = p + (size_t)n * DD * hw;
    const float* tv = t + (size_t)n * DD * hw;

    for (int s = zs - 3; s < zs + ZC + 3; ++s) {
        float2 m01[2], m23[2];
#pragma unroll
        for (int yo = 0; yo < 2; ++yo) {
            m01[yo] = make_float2(0.f, 0.f);
            m23[yo] = make_float2(0.f, 0.f);
        }

        const bool valid = (s >= 0) && (s < DD);   // block-uniform
        if (valid) {
            const float* pb = pv + (size_t)s * hw;
            const float* tb = tv + (size_t)s * hw;

            // ---- A: stage halo tile, pointwise channels formed once ----
            for (int i = tid; i < PCOLS * HR; i += NTHR) {
                int r = i / PCOLS, c = i - r * PCOLS;
                int gy = y0 + r - 3, gx = x0 + c - 3;
                float a = 0.f, b = 0.f;
                if ((unsigned)gy < (unsigned)HH && (unsigned)gx < (unsigned)WW) {
                    a = pb[gy * WW + gx];
                    b = tb[gy * WW + gx];
                }
                float u = a + b, d = a - b;
                spt[r][c] = make_float2(a, b);
                squ[r][c] = make_float2(u * u, d * d);
            }
            __syncthreads();

            // ---- B: x-conv, 176 jobs of 4 outputs each ----
            if (tid < HR * 8) {
                int r = tid >> 3, xg = tid & 7;     // row, x-group
                const float4* P4 = (const float4*)&spt[r][0];
                const float4* Q4 = (const float4*)&squ[r][0];
                float2 pt[10], qu[10];
#pragma unroll
                for (int k = 0; k < 5; ++k) {
                    float4 a = P4[2 * xg + k];
                    pt[2 * k]     = make_float2(a.x, a.y);
                    pt[2 * k + 1] = make_float2(a.z, a.w);
                    float4 b = Q4[2 * xg + k];
                    qu[2 * k]     = make_float2(b.x, b.y);
                    qu[2 * k + 1] = make_float2(b.z, b.w);
                }
#pragma unroll
                for (int e = 0; e < 4; ++e) {
                    float2 s01 = make_float2(0.f, 0.f);
                    float2 s23 = make_float2(0.f, 0.f);
#pragma unroll
                    for (int k = 0; k < 7; ++k) {
                        float w = gw.g[k];
                        s01 = f2fma(w, pt[e + k], s01);
                        s23 = f2fma(w, qu[e + k], s23);
                    }
                    c4[r][4 * xg + e] = make_float4(s01.x, s01.y, s23.x, s23.y);
                }
            }
            __syncthreads();

            // ---- C: y-conv, stream 8 rows for both y-outputs ----
#pragma unroll
            for (int r8 = 0; r8 < 8; ++r8) {
                float4 v = c4[2 * tyo + r8][tx];
                float2 v01 = make_float2(v.x, v.y);
                float2 v23 = make_float2(v.z, v.w);
                if (r8 < 7) {
                    float w = gw.g[r8];
                    m01[0] = f2fma(w, v01, m01[0]);
                    m23[0] = f2fma(w, v23, m23[0]);
                }
                if (r8 > 0) {
                    float w = gw.g[r8 - 1];
                    m01[1] = f2fma(w, v01, m01[1]);
                    m23[1] = f2fma(w, v23, m23[1]);
                }
            }
            // no barrier: next A writes spt/squ (y-conv reads only c4);
            // next B's c4 writes are fenced by next A's barrier.
        }

        // ---- z rings: consume slot0, shift+FMA, refill ----
        float2 cons01[2], cons23[2];
#pragma unroll
        for (int yo = 0; yo < 2; ++yo) {
            float2 v01 = m01[yo], v23 = m23[yo];
            cons01[yo] = f2fma(gw.g[6], v01, r01[yo][0]);
            cons23[yo] = f2fma(gw.g[6], v23, r23[yo][0]);
#pragma unroll
            for (int j = 0; j < 5; ++j) {
                r01[yo][j] = f2fma(gw.g[5 - j], v01, r01[yo][j + 1]);
                r23[yo][j] = f2fma(gw.g[5 - j], v23, r23[yo][j + 1]);
            }
            r01[yo][5] = make_float2(gw.g[0] * v01.x, gw.g[0] * v01.y);
            r23[yo][5] = make_float2(gw.g[0] * v23.x, gw.g[0] * v23.y);
        }

        if (s >= zs + 3) {   // output z = s-3
#pragma unroll
            for (int yo = 0; yo < 2; ++yo) {
                float mu1 = cons01[yo].x, mu2 = cons01[yo].y;
                float Eu  = cons23[yo].x, Ew  = cons23[yo].y;
                float mu12 = mu1 * mu2, mu1sq = mu1 * mu1, mu2sq = mu2 * mu2;
                float sumsq = 0.5f  * (Eu + Ew) - mu1sq - mu2sq; // s1+s2
                float s12   = 0.25f * (Eu - Ew) - mu12;          // sigma12
                float num = (2.f * mu12 + C1v) * (2.f * s12 + C2v);
                float den = (mu1sq + mu2sq + C1v) * (sumsq + C2v);
                ssum += num * __builtin_amdgcn_rcpf(den);
            }
        }
    }

    // ---- block reduction (4 waves) ----
#pragma unroll
    for (int off = 32; off > 0; off >>= 1)
        ssum += __shfl_down(ssum, off, 64);
    __shared__ float wsum[4];
    if ((tid & 63) == 0) wsum[tid >> 6] = ssum;
    __syncthreads();
    if (tid == 0) {
        int bid = (blockIdx.z * GY + blockIdx.y) * GX + blockIdx.x;
        partial[bid] = wsum[0] + wsum[1] + wsum[2] + wsum[3];
    }
}

__global__ __launch_bounds__(256) void ssim_final(
        const float* __restrict__ partial, float* __restrict__ out) {
    float s = 0.f;
    for (int i = threadIdx.x; i < NPART; i += 256) s += partial[i];
#pragma unroll
    for (int off = 32; off > 0; off >>= 1)
        s += __shfl_down(s, off, 64);
    __shared__ float wsum[4];
    int lane = threadIdx.x & 63, wid = threadIdx.x >> 6;
    if (lane == 0) wsum[wid] = s;
    __syncthreads();
    if (threadIdx.x == 0) {
        float tot = wsum[0] + wsum[1] + wsum[2] + wsum[3];
        out[0] = 1.0f - tot / (float)NEL;
    }
}

extern "C" void kernel_launch(void* const* d_in, const int* in_sizes, int n_in,
                              void* d_out, int out_size, void* d_ws, size_t ws_size,
                              hipStream_t stream) {
    const float* p = (const float*)d_in[0];
    const float* t = (const float*)d_in[1];
    float* out = (float*)d_out;
    float* partial = (float*)d_ws;   // NPART floats

    G7 gw;
    {
        double s = 0.0, sig = 7.0 / 6.0;
        double g[7];
        for (int i = 0; i < 7; ++i) {
            double d = (double)i - 3.0;
            g[i] = exp(-d * d / (2.0 * sig * sig));
            s += g[i];
        }
        for (int i = 0; i < 7; ++i) gw.g[i] = (float)(g[i] / s);
    }

    dim3 grid(GX, GY, NB * NZCH);   // (5, 10, 20) = 1000 blocks
    ssim_fused<<<grid, NTHR, 0, stream>>>(p, t, partial, gw);
    ssim_final<<<1, 256, 0, stream>>>(partial, out);
}

// Round 5
// 136.237 us; speedup vs baseline: 1.3775x; 1.1243x over previous
//
#include <hip/hip_runtime.h>
#include <math.h>

#define DD 160
#define HH 160
#define WW 160
#define NB 2
#define NEL (NB*DD*HH*WW)   // 8,192,000 voxels

#define XT 32               // x outputs per block
#define YT 16               // y outputs per block
#define ZC 16               // z outputs per block
#define NTHR 256
#define NZCH (DD/ZC)        // 10
#define GX (WW/XT)          // 5
#define GY (HH/YT)          // 10
#define NPART (GX*GY*NB*NZCH)  // 1000 blocks -> 4000 waves

#define HR 22               // halo rows (16 + 6)
#define CP 35               // c4 physical pitch in float4 (32 + swizzle + pad)

struct G7 { float g[7]; };

__device__ __forceinline__ float2 f2fma(float s, float2 a, float2 b) {
    return make_float2(fmaf(s, a.x, b.x), fmaf(s, a.y, b.y));
}

// Fully fused separable 3D SSIM, v4:
//  * NO raw LDS staging: x-conv jobs load 3 aligned float4 per array straight
//    from global (L1 absorbs the 1.7x halo overlap; 7KB/CU footprint).
//    Quads are 4-aligned and row bounds are 4-aligned -> all-or-nothing
//    predicate per quad, zero-fill implements x/y padding.
//  * 4 channels: (p,t) and ((p+t)^2,(p-t)^2) -> float2 packed FMA.
//  * c4 column swizzle pc = c + (c>>3): conflict-free b128 writes AND reads.
//  * double-buffered c4 -> ONE __syncthreads per z-slice.
//  * z-conv via float2 register rings; SSIM consumed in-register.
__global__ __launch_bounds__(NTHR, 4) void ssim_fused(
        const float* __restrict__ p, const float* __restrict__ t,
        float* __restrict__ partial, G7 gw) {
    const int tid = threadIdx.x;
    const int tx  = tid & 31;            // x output column (phase C)
    const int tyo = tid >> 5;            // 0..7, owns y = 2tyo, 2tyo+1
    const int x0 = blockIdx.x * XT;
    const int y0 = blockIdx.y * YT;
    const int n  = blockIdx.z / NZCH;
    const int zs = (blockIdx.z % NZCH) * ZC;

    __shared__ float4 c4[2][HR][CP];     // x-conv result, 4 ch packed, dbuf

    // z rings: [y-out][slot], slot5 freshest
    float2 r01[2][6], r23[2][6];
#pragma unroll
    for (int yo = 0; yo < 2; ++yo)
#pragma unroll
        for (int j = 0; j < 6; ++j) {
            r01[yo][j] = make_float2(0.f, 0.f);
            r23[yo][j] = make_float2(0.f, 0.f);
        }

    const float C1v = 1e-4f, C2v = 9e-4f;
    float ssum = 0.f;
    const int hw = HH * WW;
    const float* pv = p + (size_t)n * DD * hw;
    const float* tv = t + (size_t)n * DD * hw;

    // phase-B job decode (tid < 176): row r, x-group xg
    const int br = tid >> 3;             // 0..21 (tid<176)
    const int bxg = tid & 7;             // 0..7
    const int bgy = y0 + br - 3;
    const bool browok = (unsigned)bgy < (unsigned)HH && tid < HR * 8;
    const int cbase = x0 + 4 * bxg - 4;  // first loaded column (4-aligned)
    const int pcr = tx + (tx >> 3);      // C-phase swizzled column

    for (int s = zs - 3; s < zs + ZC + 3; ++s) {
        const int par = s & 1;
        float2 m01[2], m23[2];
#pragma unroll
        for (int yo = 0; yo < 2; ++yo) {
            m01[yo] = make_float2(0.f, 0.f);
            m23[yo] = make_float2(0.f, 0.f);
        }

        const bool valid = (s >= 0) && (s < DD);   // block-uniform
        if (valid) {
            // ---- B: x-conv from global, 176 jobs of 4 outputs ----
            if (tid < HR * 8) {
                const float* prow = pv + (size_t)s * hw + bgy * WW;
                const float* trow = tv + (size_t)s * hw + bgy * WW;
                float2 pt[12], qu[12];
#pragma unroll
                for (int q = 0; q < 3; ++q) {
                    int c0 = cbase + 4 * q;
                    float4 a = make_float4(0.f, 0.f, 0.f, 0.f);
                    float4 b = a;
                    if (browok && (unsigned)c0 < (unsigned)WW) {
                        a = *(const float4*)(prow + c0);
                        b = *(const float4*)(trow + c0);
                    }
                    float u, d;
                    pt[4*q+0] = make_float2(a.x, b.x);
                    u = a.x + b.x; d = a.x - b.x;
                    qu[4*q+0] = make_float2(u * u, d * d);
                    pt[4*q+1] = make_float2(a.y, b.y);
                    u = a.y + b.y; d = a.y - b.y;
                    qu[4*q+1] = make_float2(u * u, d * d);
                    pt[4*q+2] = make_float2(a.z, b.z);
                    u = a.z + b.z; d = a.z - b.z;
                    qu[4*q+2] = make_float2(u * u, d * d);
                    pt[4*q+3] = make_float2(a.w, b.w);
                    u = a.w + b.w; d = a.w - b.w;
                    qu[4*q+3] = make_float2(u * u, d * d);
                }
#pragma unroll
                for (int e = 0; e < 4; ++e) {
                    float2 s01 = make_float2(0.f, 0.f);
                    float2 s23 = make_float2(0.f, 0.f);
#pragma unroll
                    for (int k = 0; k < 7; ++k) {
                        float w = gw.g[k];
                        s01 = f2fma(w, pt[e + k + 1], s01);
                        s23 = f2fma(w, qu[e + k + 1], s23);
                    }
                    int c = 4 * bxg + e;
                    c4[par][br][c + (c >> 3)] =
                        make_float4(s01.x, s01.y, s23.x, s23.y);
                }
            }
            __syncthreads();   // block-uniform (valid is uniform)

            // ---- C: y-conv, stream 8 rows for both y-outputs ----
#pragma unroll
            for (int r8 = 0; r8 < 8; ++r8) {
                float4 v = c4[par][2 * tyo + r8][pcr];
                float2 v01 = make_float2(v.x, v.y);
                float2 v23 = make_float2(v.z, v.w);
                if (r8 < 7) {
                    float w = gw.g[r8];
                    m01[0] = f2fma(w, v01, m01[0]);
                    m23[0] = f2fma(w, v23, m23[0]);
                }
                if (r8 > 0) {
                    float w = gw.g[r8 - 1];
                    m01[1] = f2fma(w, v01, m01[1]);
                    m23[1] = f2fma(w, v23, m23[1]);
                }
            }
            // no trailing barrier: next slice writes the OTHER c4 buffer;
            // the WAR on this buffer (2 slices later) is fenced by the
            // intervening slice's barrier.
        }

        // ---- z rings: consume slot0, shift+FMA, refill ----
        float2 cons01[2], cons23[2];
#pragma unroll
        for (int yo = 0; yo < 2; ++yo) {
            float2 v01 = m01[yo], v23 = m23[yo];
            cons01[yo] = f2fma(gw.g[6], v01, r01[yo][0]);
            cons23[yo] = f2fma(gw.g[6], v23, r23[yo][0]);
#pragma unroll
            for (int j = 0; j < 5; ++j) {
                r01[yo][j] = f2fma(gw.g[5 - j], v01, r01[yo][j + 1]);
                r23[yo][j] = f2fma(gw.g[5 - j], v23, r23[yo][j + 1]);
            }
            r01[yo][5] = make_float2(gw.g[0] * v01.x, gw.g[0] * v01.y);
            r23[yo][5] = make_float2(gw.g[0] * v23.x, gw.g[0] * v23.y);
        }

        if (s >= zs + 3) {   // output z = s-3
#pragma unroll
            for (int yo = 0; yo < 2; ++yo) {
                float mu1 = cons01[yo].x, mu2 = cons01[yo].y;
                float Eu  = cons23[yo].x, Ew  = cons23[yo].y;
                float mu12 = mu1 * mu2, mu1sq = mu1 * mu1, mu2sq = mu2 * mu2;
                float sumsq = 0.5f  * (Eu + Ew) - mu1sq - mu2sq; // s1+s2
                float s12   = 0.25f * (Eu - Ew) - mu12;          // sigma12
                float num = (2.f * mu12 + C1v) * (2.f * s12 + C2v);
                float den = (mu1sq + mu2sq + C1v) * (sumsq + C2v);
                ssum += num * __builtin_amdgcn_rcpf(den);
            }
        }
    }

    // ---- block reduction (4 waves) ----
#pragma unroll
    for (int off = 32; off > 0; off >>= 1)
        ssum += __shfl_down(ssum, off, 64);
    __shared__ float wsum[4];
    if ((tid & 63) == 0) wsum[tid >> 6] = ssum;
    __syncthreads();
    if (tid == 0) {
        int bid = (blockIdx.z * GY + blockIdx.y) * GX + blockIdx.x;
        partial[bid] = wsum[0] + wsum[1] + wsum[2] + wsum[3];
    }
}

__global__ __launch_bounds__(256) void ssim_final(
        const float* __restrict__ partial, float* __restrict__ out) {
    float s = 0.f;
    for (int i = threadIdx.x; i < NPART; i += 256) s += partial[i];
#pragma unroll
    for (int off = 32; off > 0; off >>= 1)
        s += __shfl_down(s, off, 64);
    __shared__ float wsum[4];
    int lane = threadIdx.x & 63, wid = threadIdx.x >> 6;
    if (lane == 0) wsum[wid] = s;
    __syncthreads();
    if (threadIdx.x == 0) {
        float tot = wsum[0] + wsum[1] + wsum[2] + wsum[3];
        out[0] = 1.0f - tot / (float)NEL;
    }
}

extern "C" void kernel_launch(void* const* d_in, const int* in_sizes, int n_in,
                              void* d_out, int out_size, void* d_ws, size_t ws_size,
                              hipStream_t stream) {
    const float* p = (const float*)d_in[0];
    const float* t = (const float*)d_in[1];
    float* out = (float*)d_out;
    float* partial = (float*)d_ws;   // NPART floats

    G7 gw;
    {
        double s = 0.0, sig = 7.0 / 6.0;
        double g[7];
        for (int i = 0; i < 7; ++i) {
            double d = (double)i - 3.0;
            g[i] = exp(-d * d / (2.0 * sig * sig));
            s += g[i];
        }
        for (int i = 0; i < 7; ++i) gw.g[i] = (float)(g[i] / s);
    }

    dim3 grid(GX, GY, NB * NZCH);   // (5, 10, 20) = 1000 blocks
    ssim_fused<<<grid, NTHR, 0, stream>>>(p, t, partial, gw);
    ssim_final<<<1, 256, 0, stream>>>(partial, out);
}